// Round 5
// baseline (1051.689 us; speedup 1.0000x reference)
//
#include <hip/hip_runtime.h>
#include <hip/hip_fp16.h>

// ---------------------------------------------------------------------------
// RecurrentRepresentationAggregator: 64-step LSTM-ish recurrence, B=512.
//   gates_t = [r_{t-1}, h_{t-1}, z_t] @ W_rnn^T + b_rnn      (N=2048, K=1280)
//   c_t = sig(f)*c + sig(i)*tanh(s);  h_t = sig(o)*tanh(c_t)
//   r_t = r_{t-1} + h_t @ W_feat^T + b_feat                   (N=256, K=512)
//
// Fold: gates_t = Gz_t + r_{t-2}·Wr + h_{t-1}·(Wh + Wf^T Wr). Gz for chunk c+1
// is produced INSIDE chunk c's step launches: steps 0-3 repack z (r-blocks),
// steps 4-7 all 512 blocks each compute one 64x64 gz tile (2048 = full chunk).
// Grid = 512 blocks = exactly 2/CU (balanced); gate blocks XCD-swizzled
// (bm = bid&7) so A-panels stay in one XCD's L2. h/rd carried in fp16 MFMA
// fragment layout -> K-loop is pure {coalesced dwordx4 load -> MFMA}.
// Frag map (16x16x32): value(row,k) at lane=(row&15)+16*((k&31)>>3), e=k&7,
// frag index = (mt*KCH + kc)*64 + lane. Gate cols permuted n = 4j+q.
// ---------------------------------------------------------------------------

using f32x4 = __attribute__((ext_vector_type(4))) float;
using f16x8 = __attribute__((ext_vector_type(8))) _Float16;
using fp16x2 = __attribute__((ext_vector_type(2))) __fp16;

union U4H8 { uint4 u; f16x8 h; fp16x2 p[4]; };

__device__ __forceinline__ float sigm(float x){ return 1.0f/(1.0f + __expf(-x)); }
__device__ __forceinline__ float tanhfast(float x){
  x = fminf(fmaxf(x, -30.f), 30.f);
  float e = __expf(2.0f*x);
  return (e - 1.0f)/(e + 1.0f);
}

#define MFMA16(a,b,c) __builtin_amdgcn_mfma_f32_16x16x32_f16((a).h,(b).h,(c),0,0,0)

// --- prologue kernels -------------------------------------------------------

// W_feat [256][512] -> WfT32 [512][256]
__global__ void k_wft(const float* __restrict__ wf, float* __restrict__ wft){
  int idx = blockIdx.x*256 + threadIdx.x;      // 131072
  int c = idx & 511; int j = idx >> 9;
  wft[c*256 + j] = wf[idx];
}

// bias'[n] = b_rnn[g(n)] + sum_j b_feat[j] * W_rnn[g(n)][j]
__global__ void k_bias(const float* __restrict__ wrnn, const float* __restrict__ brnn,
                       const float* __restrict__ bfeat, float* __restrict__ biasp){
  int n = blockIdx.x*256 + threadIdx.x;        // 2048
  int g = (n&3)*512 + (n>>2);
  const float* wr = wrnn + (size_t)g*1280;
  float acc = brnn[g];
  for (int j=0;j<256;j++) acc += bfeat[j]*wr[j];
  biasp[n] = acc;
}

// whp_part[s][kk][n] = sum_{j in slice s} WfT32[kk][j] * W_rnn[g(n)][j]
// grid 1024 = 4 K-slices x (8 kk-tiles x 32 n-tiles); 4 blocks/CU.
__global__ void k_whp4(const float* __restrict__ wrnn, const float* __restrict__ wft,
                       float* __restrict__ whp_part){
  int s = blockIdx.x >> 8;
  int tl = blockIdx.x & 255;
  int bn = tl & 31, bk = tl >> 5;
  __shared__ float wrs[64][37];
  __shared__ float wfs[64][37];
  int tid = threadIdx.x;
  int tn = tid & 15, tk = tid >> 4;
  float accv[4][4];
  #pragma unroll
  for (int x=0;x<4;x++) for (int y=0;y<4;y++) accv[x][y]=0.f;
  for (int jc = s*64; jc < s*64+64; jc += 32){
    __syncthreads();
    for (int idx = tid; idx < 64*32; idx += 256){
      int r = idx >> 5, j = idx & 31;
      int n = bn*64 + r; int g = (n&3)*512 + (n>>2);
      wrs[r][j] = wrnn[(size_t)g*1280 + jc + j];
      wfs[r][j] = wft[(bk*64 + r)*256 + jc + j];
    }
    __syncthreads();
    for (int j=0;j<32;j++){
      float a[4], b[4];
      #pragma unroll
      for (int x=0;x<4;x++){ a[x] = wfs[tk*4+x][j]; b[x] = wrs[tn*4+x][j]; }
      #pragma unroll
      for (int x=0;x<4;x++)
        #pragma unroll
        for (int y=0;y<4;y++) accv[x][y] += a[x]*b[y];
    }
  }
  float* dst = whp_part + (size_t)s*1048576;
  for (int x=0;x<4;x++){
    int kk = bk*64 + tk*4 + x;
    for (int y=0;y<4;y++){
      int n = bn*64 + tn*4 + y;
      dst[(size_t)kk*2048 + n] = accv[x][y];
    }
  }
}

// whp32 = sum of 4 K-slices
__global__ void k_whpadd(const float* __restrict__ p, float* __restrict__ o){
  int i = (blockIdx.x*256 + threadIdx.x)*4;    // grid 1024
  float4 a = *(const float4*)(p + i);
  float4 b = *(const float4*)(p + 1048576 + i);
  float4 c = *(const float4*)(p + 2097152 + i);
  float4 d = *(const float4*)(p + 3145728 + i);
  float4 r;
  r.x = a.x+b.x+c.x+d.x; r.y = a.y+b.y+c.y+d.y;
  r.z = a.z+b.z+c.z+d.z; r.w = a.w+b.w+c.w+d.w;
  *(float4*)(o + i) = r;
}

// rd0 = r0 - h0 @ Wf^T - b_feat  (= r_{-1}), fp32 + fp16-frag copies
__global__ void k_rinit(const float* __restrict__ r0, const float* __restrict__ h0,
                        const float* __restrict__ wft, const float* __restrict__ bfeat,
                        float* __restrict__ rd32, __half* __restrict__ rd16){
  __shared__ float hs[512];
  int row = blockIdx.x; int j = threadIdx.x;   // 512 blocks x 256 threads
  for (int k = threadIdx.x; k < 512; k += 256) hs[k] = h0[row*512 + k];
  __syncthreads();
  float acc = 0.f;
  for (int k=0;k<512;k++) acc += hs[k]*wft[k*256 + j];
  float rr = r0[row*256 + j] - acc - bfeat[j];
  rd32[row*256 + j] = rr;
  int ridx = (((row>>4)*8 + (j>>5))*64 + (row&15) + (((j&31)>>3)<<4))*8 + (j&7);
  rd16[ridx] = __float2half(rr);
}

// h0 -> fp16-frag; c0 -> c32 (both 512x512)
__global__ void k_packh0(const float* __restrict__ h0, const float* __restrict__ c0,
                         __half* __restrict__ h16, float* __restrict__ c32){
  int idx = blockIdx.x*256 + threadIdx.x;      // 262144
  int e = idx & 7, l = (idx>>3) & 63, kc = (idx>>9) & 15, mt = idx >> 13;
  int row = mt*16 + (l&15);
  int k = kc*32 + ((l>>4)<<3) + e;
  h16[idx] = __float2half(h0[row*512 + k]);
  c32[idx] = c0[idx];
}

// Pack B matrices into frag order: dst[(nt*KCH + kc)*512 + lane*8 + e]
// mode 0: recurrent B (K=768): k<256 -> Wr ; else Whp + Wh
// mode 2: Wz (K=512);  mode 3: Wf^T (K=512, N=256)
__global__ void k_pack(const float* __restrict__ wrnn, const float* __restrict__ whp32,
                       const float* __restrict__ wfeat, __half* __restrict__ dst,
                       int mode, int NT16, int KCH){
  int tot = NT16*KCH*512;
  for (int idx = blockIdx.x*256 + threadIdx.x; idx < tot; idx += gridDim.x*256){
    int e = idx & 7; int l = (idx>>3) & 63;
    int kc = (idx>>9) % KCH; int nt = (idx>>9) / KCH;
    int k = kc*32 + ((l>>4)<<3) + e;
    int n = nt*16 + (l&15);
    float v;
    if (mode == 0){
      int g = (n&3)*512 + (n>>2);
      if (k < 256) v = wrnn[(size_t)g*1280 + k];
      else         v = whp32[(size_t)(k-256)*2048 + n] + wrnn[(size_t)g*1280 + k];
    } else if (mode == 2){
      int g = (n&3)*512 + (n>>2);
      v = wrnn[(size_t)g*1280 + 768 + k];
    } else {
      v = wfeat[(size_t)n*512 + k];
    }
    dst[idx] = __float2half(v);
  }
}

// --- z -> fp16 frag layout for one 8-step chunk (prologue, chunk 0) ---------
__global__ void k_zpack(const float* __restrict__ z, __half* __restrict__ z16, int t0){
  int u = blockIdx.x*256 + threadIdx.x;        // 65536
  int k0 = (u & 63) * 8;
  int b4 = (u >> 6) & 127;
  int tt = (u >> 13) & 7;
  int b = b4 * 4;
  int frag = (tt*32 + (b>>4))*16 + (k0>>5);
  uint4 wv[4];
  #pragma unroll
  for (int j=0;j<4;j++){
    const float4* src = (const float4*)(z + ((size_t)((b+j)*64 + t0 + tt))*512 + k0);
    float4 f0 = src[0], f1 = src[1];
    U4H8 a;
    a.p[0] = __builtin_amdgcn_cvt_pkrtz(f0.x, f0.y);
    a.p[1] = __builtin_amdgcn_cvt_pkrtz(f0.z, f0.w);
    a.p[2] = __builtin_amdgcn_cvt_pkrtz(f1.x, f1.y);
    a.p[3] = __builtin_amdgcn_cvt_pkrtz(f1.z, f1.w);
    wv[j] = a.u;
  }
  uint4* dst = (uint4*)z16 + (size_t)frag*64 + (b & 15) + (((k0 & 31) >> 3) << 4);
  #pragma unroll
  for (int j=0;j<4;j++) dst[j] = wv[j];
}

// --- Gz chunk GEMM (prologue, chunk 0): M=4096, N=2048, K=512 ---------------
__global__ __launch_bounds__(512) void k_gz3(const __half* __restrict__ z16,
    const __half* __restrict__ bpz, const float* __restrict__ biasp,
    __half* __restrict__ gz){
  const int tid = threadIdx.x, lane = tid & 63, w = tid >> 6;
  const int wr = w >> 2, wc = w & 3;
  const int bm = blockIdx.x >> 4, bn = blockIdx.x & 15;   // 32 x 16
  const int tt = bm >> 2, bq = bm & 3;
  const int mt0 = tt*32 + bq*8 + wr*4;
  const int nt0 = bn*8 + wc*2;
  const uint4* A = (const uint4*)z16 + (size_t)(mt0*16)*64 + lane;
  const uint4* B = (const uint4*)bpz + (size_t)(nt0*16)*64 + lane;
  f32x4 acc[4][2];
  #pragma unroll
  for (int mi=0;mi<4;mi++){ acc[mi][0]=(f32x4){0,0,0,0}; acc[mi][1]=(f32x4){0,0,0,0}; }
  #pragma unroll 2
  for (int kc=0; kc<16; ++kc){
    U4H8 b0v, b1v;
    b0v.u = B[kc*64];
    b1v.u = B[(16+kc)*64];
    #pragma unroll
    for (int mi=0; mi<4; mi++){
      U4H8 a;
      a.u = A[(mi*16 + kc)*64];
      acc[mi][0] = MFMA16(a, b0v, acc[mi][0]);
      acc[mi][1] = MFMA16(a, b1v, acc[mi][1]);
    }
  }
  #pragma unroll
  for (int ns=0; ns<2; ns++){
    int n = (nt0 + ns)*16 + (lane & 15);
    float bp = biasp[n];
    #pragma unroll
    for (int mi=0; mi<4; mi++){
      #pragma unroll
      for (int i=0; i<4; i++){
        int brow = bq*128 + wr*64 + mi*16 + ((lane>>4)<<2) + i;
        gz[((size_t)(tt*512 + brow))*2048 + n] = __float2half(acc[mi][ns][i] + bp);
      }
    }
  }
}

// --- the per-timestep kernel ------------------------------------------------
// mode 0, grid 512: bid<256 gate (bm=bid&7 XCD-swizzle, bn=bid>>3);
//   bid 256..287 r-GEMM (+zpack chunk c+1 on steps 0-3);
//   ALL blocks: one 64x64 gz tile of chunk c+1 on steps 4-7.
// mode 1, grid 32: final r -> out_r.
__global__ __launch_bounds__(512, 4) void k_step2(
    const __half* __restrict__ rd16_in, const __half* __restrict__ h16_in,
    float* __restrict__ rd32,
    __half* __restrict__ rd16_out, __half* __restrict__ h16_out,
    float* __restrict__ c32,
    const __half* __restrict__ gz_t,     // this step's gz slice
    __half* __restrict__ gz_wr,          // next chunk's gz buffer (base)
    const __half* __restrict__ z16,      // frag-z for next chunk
    const float* __restrict__ z,
    const __half* __restrict__ bp_rec, const __half* __restrict__ bf_pack,
    const __half* __restrict__ bpz, const float* __restrict__ biasp,
    const float* __restrict__ bfeat,
    float* __restrict__ out_h, float* __restrict__ out_c, float* __restrict__ out_r,
    int step, int mode){
  __shared__ float cls[64][69];
  const int tid = threadIdx.x, lane = tid & 63, w = tid >> 6, wr = w >> 2, wc = w & 3;
  const int bid = blockIdx.x;
  const int c = step >> 3;
  const bool produce = (mode == 0) && (c < 7);
  const bool heavy   = produce && ((step & 7) >= 4);
  const bool do_gate = (mode == 0) && (bid < 256);
  const bool do_r    = (mode == 1) ? true : (bid >= 256 && bid < 288);
  const int  rb      = (mode == 1) ? bid : bid - 256;

  if (do_gate){
    const int bm = bid & 7, bn = bid >> 3;
    f32x4 acc[2];
    acc[0] = (f32x4){0.f,0.f,0.f,0.f};
    acc[1] = (f32x4){0.f,0.f,0.f,0.f};
    const int mtA = bm*4 + wr*2;
    const int nt  = bn*4 + wc;
    const uint4* a0p = (const uint4*)rd16_in + (size_t)(mtA*8)*64 + lane;
    const uint4* a1p = a0p + 8*64;
    const uint4* h0p = (const uint4*)h16_in + (size_t)(mtA*16)*64 + lane;
    const uint4* h1p = h0p + 16*64;
    const uint4* bp  = (const uint4*)bp_rec + (size_t)(nt*24)*64 + lane;
    #pragma unroll 4
    for (int kc=0; kc<8; ++kc){
      U4H8 a0,a1,b;
      a0.u = a0p[kc*64]; a1.u = a1p[kc*64]; b.u = bp[kc*64];
      acc[0] = MFMA16(a0,b,acc[0]);
      acc[1] = MFMA16(a1,b,acc[1]);
    }
    #pragma unroll 4
    for (int kc=0; kc<16; ++kc){
      U4H8 a0,a1,b;
      a0.u = h0p[kc*64]; a1.u = h1p[kc*64]; b.u = bp[(8+kc)*64];
      acc[0] = MFMA16(a0,b,acc[0]);
      acc[1] = MFMA16(a1,b,acc[1]);
    }
    #pragma unroll
    for (int ms=0; ms<2; ms++)
      #pragma unroll
      for (int i=0; i<4; i++)
        cls[wr*32 + ms*16 + ((lane>>4)<<2) + i][wc*16 + (lane&15)] = acc[ms][i];
    __syncthreads();
    const bool last = (out_h != nullptr);
    #pragma unroll
    for (int rep=0; rep<2; rep++){
      int idx = rep*512 + tid;
      int jl = idx & 15, row = idx >> 4;
      int grow = bm*64 + row;
      int j = bn*16 + jl;
      const __half2* gp = (const __half2*)(gz_t + (size_t)grow*2048 + bn*64 + jl*4);
      __half2 p0 = gp[0], p1 = gp[1];
      float g0 = cls[row][jl*4+0] + __half2float(p0.x);
      float g1 = cls[row][jl*4+1] + __half2float(p0.y);
      float g2 = cls[row][jl*4+2] + __half2float(p1.x);
      float g3 = cls[row][jl*4+3] + __half2float(p1.y);
      float cold = c32[(size_t)grow*512 + j];
      float f  = sigm(g0);
      float ii = sigm(g1);
      float s  = tanhfast(g2);
      float o  = sigm(g3);
      float cn = f*cold + ii*s;
      float hn = o*tanhfast(cn);
      c32[(size_t)grow*512 + j] = cn;
      int hidx = (((grow>>4)*16 + (j>>5))*64 + (grow&15) + (((j&31)>>3)<<4))*8 + (j&7);
      h16_out[hidx] = __float2half(hn);
      if (last){
        out_h[(size_t)grow*512 + j] = hn;
        out_c[(size_t)grow*512 + j] = cn;
      }
    }
  } else if (do_r){
    const int rm = rb >> 2, rn = rb & 3;
    f32x4 acc[2];
    acc[0] = (f32x4){0.f,0.f,0.f,0.f};
    acc[1] = (f32x4){0.f,0.f,0.f,0.f};
    const int mtA = rm*4 + wr*2;
    const int nt  = rn*4 + wc;
    const uint4* h0p = (const uint4*)h16_in + (size_t)(mtA*16)*64 + lane;
    const uint4* h1p = h0p + 16*64;
    const uint4* bf  = (const uint4*)bf_pack + (size_t)(nt*16)*64 + lane;
    #pragma unroll 4
    for (int kc=0; kc<16; ++kc){
      U4H8 a0,a1,b;
      a0.u = h0p[kc*64]; a1.u = h1p[kc*64]; b.u = bf[kc*64];
      acc[0] = MFMA16(a0,b,acc[0]);
      acc[1] = MFMA16(a1,b,acc[1]);
    }
    #pragma unroll
    for (int ms=0; ms<2; ms++){
      int col = rn*64 + wc*16 + (lane&15);
      float bfv = bfeat[col];
      #pragma unroll
      for (int i=0; i<4; i++){
        int grow = rm*64 + wr*32 + ms*16 + ((lane>>4)<<2) + i;
        size_t ridx32 = (size_t)grow*256 + col;
        float rr = acc[ms][i] + rd32[ridx32] + bfv;
        if (mode == 1){
          out_r[ridx32] = rr;
        } else {
          rd32[ridx32] = rr;
          int ridx = (((grow>>4)*8 + (col>>5))*64
                      + (grow&15) + (((col&31)>>3)<<4))*8 + (col&7);
          rd16_out[ridx] = __float2half(rr);
        }
      }
    }
    // zpack slice for chunk c+1 (steps 0-3)
    if (produce && ((step & 7) < 4)){
      int u = (step & 3)*16384 + rb*512 + tid;
      int k0 = (u & 63) * 8;
      int b4 = (u >> 6) & 127;
      int tt = (u >> 13) & 7;
      int b = b4 * 4;
      int frag = (tt*32 + (b>>4))*16 + (k0>>5);
      uint4 wv[4];
      #pragma unroll
      for (int j=0;j<4;j++){
        const float4* src = (const float4*)(z + ((size_t)((b+j)*64 + (c+1)*8 + tt))*512 + k0);
        float4 f0 = src[0], f1 = src[1];
        U4H8 a;
        a.p[0] = __builtin_amdgcn_cvt_pkrtz(f0.x, f0.y);
        a.p[1] = __builtin_amdgcn_cvt_pkrtz(f0.z, f0.w);
        a.p[2] = __builtin_amdgcn_cvt_pkrtz(f1.x, f1.y);
        a.p[3] = __builtin_amdgcn_cvt_pkrtz(f1.z, f1.w);
        wv[j] = a.u;
      }
      uint4* dst = (uint4*)z16 + (size_t)frag*64 + (b & 15) + (((k0 & 31) >> 3) << 4);
      #pragma unroll
      for (int j=0;j<4;j++) dst[j] = wv[j];
    }
  }

  // --- gz tile of chunk c+1 (steps 4-7): every block, one 64x64 tile --------
  if (heavy){
    int tl = (step & 3)*512 + bid;
    int mtile = tl >> 5, ntile = tl & 31;
    int mfr = mtile*4 + wr*2;
    int nt  = ntile*4 + wc;
    const uint4* A0 = (const uint4*)z16 + (size_t)(mfr*16)*64 + lane;
    const uint4* A1 = A0 + 16*64;
    const uint4* B  = (const uint4*)bpz + (size_t)(nt*16)*64 + lane;
    f32x4 g0v = (f32x4){0.f,0.f,0.f,0.f};
    f32x4 g1v = (f32x4){0.f,0.f,0.f,0.f};
    #pragma unroll 4
    for (int kc=0; kc<16; ++kc){
      U4H8 a0,a1,b;
      a0.u = A0[kc*64]; a1.u = A1[kc*64]; b.u = B[kc*64];
      g0v = MFMA16(a0,b,g0v);
      g1v = MFMA16(a1,b,g1v);
    }
    int n = nt*16 + (lane & 15);
    float bpv = biasp[n];
    int tt = mtile >> 3;
    #pragma unroll
    for (int ms=0; ms<2; ms++){
      f32x4 gv = ms ? g1v : g0v;
      #pragma unroll
      for (int i=0; i<4; i++){
        int brow = (mtile & 7)*64 + wr*32 + ms*16 + ((lane>>4)<<2) + i;
        gz_wr[((size_t)(tt*512 + brow))*2048 + n] = __float2half(gv[i] + bpv);
      }
    }
  }
}

// ---------------------------------------------------------------------------
extern "C" void kernel_launch(void* const* d_in, const int* in_sizes, int n_in,
                              void* d_out, int out_size, void* d_ws, size_t ws_size,
                              hipStream_t stream){
  const float* z     = (const float*)d_in[0];
  const float* r0    = (const float*)d_in[1];
  const float* h0    = (const float*)d_in[2];
  const float* c0    = (const float*)d_in[3];
  const float* wrnn  = (const float*)d_in[4];
  const float* brnn  = (const float*)d_in[5];
  const float* wfeat = (const float*)d_in[6];
  const float* bfeat = (const float*)d_in[7];
  float* out = (float*)d_out;

  char* wsb = (char*)d_ws;
  size_t off = 0;
  auto alloc = [&](size_t bytes)->char*{
    char* p = wsb + off; off = (off + bytes + 255) & ~(size_t)255; return p;
  };
  __half* z16     = (__half*)alloc((size_t)512*2048*4);        // 4 MB (frag z chunk)
  __half* bp_rec  = (__half*)alloc((size_t)128*24*512*2);      // 3 MB
  __half* bpz     = (__half*)alloc((size_t)128*16*512*2);      // 2 MB
  __half* bf_pack = (__half*)alloc((size_t)16*16*512*2);
  float*  biasp   = (float*) alloc(2048*4);
  float*  wft32   = (float*) alloc((size_t)512*256*4);
  __half* h16A    = (__half*)alloc((size_t)512*512*2);
  __half* h16B    = (__half*)alloc((size_t)512*512*2);
  __half* rd16A   = (__half*)alloc((size_t)512*256*2);
  __half* rd16B   = (__half*)alloc((size_t)512*256*2);
  float*  rd32    = (float*) alloc((size_t)512*256*4);         // in-place
  float*  c32     = (float*) alloc((size_t)512*512*4);
  __half* gzb     = (__half*)alloc((size_t)2*8*512*2048*2);    // 32 MB, 2 chunks
  (void)ws_size;
  // prologue-only aliases inside gz region (dead before k_gz3 writes chunk 0):
  float* whp32    = (float*)gzb;                 // 4 MB
  float* whp_part = (float*)gzb + 1048576;       // 16 MB

  // prologue
  k_wft   <<<dim3(512),  dim3(256), 0, stream>>>(wfeat, wft32);
  k_bias  <<<dim3(8),    dim3(256), 0, stream>>>(wrnn, brnn, bfeat, biasp);
  k_whp4  <<<dim3(1024), dim3(256), 0, stream>>>(wrnn, wft32, whp_part);
  k_whpadd<<<dim3(1024), dim3(256), 0, stream>>>(whp_part, whp32);
  k_rinit <<<dim3(512),  dim3(256), 0, stream>>>(r0, h0, wft32, bfeat, rd32, rd16A);
  k_packh0<<<dim3(1024), dim3(256), 0, stream>>>(h0, c0, h16A, c32);
  k_pack  <<<dim3(1024), dim3(256), 0, stream>>>(wrnn, whp32, wfeat, bp_rec, 0, 128, 24);
  k_pack  <<<dim3(1024), dim3(256), 0, stream>>>(wrnn, whp32, wfeat, bpz,    2, 128, 16);
  k_pack  <<<dim3(64),   dim3(256), 0, stream>>>(wrnn, whp32, wfeat, bf_pack,3,  16, 16);
  k_zpack <<<dim3(256),  dim3(256), 0, stream>>>(z, z16, 0);
  k_gz3   <<<dim3(512),  dim3(512), 0, stream>>>(z16, bpz, biasp, gzb);

  __half* h16in = h16A;  __half* h16out = h16B;
  __half* rd16in = rd16A; __half* rd16out = rd16B;
  for (int t = 1; t <= 64; ++t){
    const int step = t-1, c = step>>3;
    const __half* gzt  = gzb + (size_t)(c&1)*8388608 + (size_t)(step&7)*1048576;
    __half*       gzwr = gzb + (size_t)((c+1)&1)*8388608;
    const bool last = (t == 64);
    k_step2<<<dim3(512), dim3(512), 0, stream>>>(
        rd16in, h16in, rd32, rd16out, h16out, c32, gzt, gzwr, z16, z,
        bp_rec, bf_pack, bpz, biasp, bfeat,
        last ? out + 131072 : (float*)nullptr,
        last ? out + 393216 : (float*)nullptr,
        (float*)nullptr, step, 0);
    __half* th;
    th = h16in; h16in = h16out; h16out = th;
    th = rd16in; rd16in = rd16out; rd16out = th;
  }
  // final: r_64 = r_63 + h_64 @ Wf^T + b_feat -> d_out[0:131072)
  k_step2<<<dim3(32), dim3(512), 0, stream>>>(
      rd16in, h16in, rd32, rd16out, h16out, c32, gzb, gzb, z16, z,
      bp_rec, bf_pack, bpz, biasp, bfeat,
      (float*)nullptr, (float*)nullptr, out, 63, 1);
}